// Round 5
// baseline (102.370 us; speedup 1.0000x reference)
//
#include <hip/hip_runtime.h>
#include <math.h>

typedef float vfloat4 __attribute__((ext_vector_type(4)));

// ---------------- compile-time J tables (reference _np_J, float64) ----------
constexpr double csqrt(double a) {
    double x = a > 1.0 ? a : 1.0;
    for (int i = 0; i < 48; ++i) x = 0.5 * (x + a / x);
    return x;
}

constexpr double j_entry_d(int ell, int mi, int mpi) {
    if (ell == 0) return 1.0;
    double fact[8] = {1.0, 1.0, 2.0, 6.0, 24.0, 120.0, 720.0, 5040.0};
    int m  = ell - mi;
    int mp = ell - mpi;
    double pref  = csqrt(fact[ell + m] * fact[ell - m] * fact[ell + mp] * fact[ell - mp]);
    double scale = 1.0 / (double)(1 << ell);
    int k0 = (m - mp) > 0 ? (m - mp) : 0;
    int k1 = (ell + m) < (ell - mp) ? (ell + m) : (ell - mp);
    double val = 0.0;
    for (int k = k0; k <= k1; ++k) {
        double denom = fact[ell + m - k] * fact[ell - mp - k] * fact[k + mp - m] * fact[k];
        double t = pref / denom * scale;
        val += ((m - mp + k) & 1) ? -t : t;
    }
    return (mi & 1) ? -val : val;
}

// Per-lane packed constants. Lane l: row r = l>>2, col group c = l&3.
// [0..6]   jmu[s]  = J_L[li,   L-m_s]            (m_s = 3-s; 0 outside block)
// [7..13]  jrv[s]  = sign(m_i) * J_L[2L-li, L-m_s]   (alpha sign pre-folded)
// [14..41] M[s][j] = J_L[L-m_s, 4c+j - L^2]      (0 outside block)
// [42..45] sA0..sA3 multiplicative masks for |m_i| == 0..3
struct alignas(16) Tabs { float t[64][48]; };

constexpr Tabs make_tabs() {
    Tabs T{};
    for (int lane = 0; lane < 64; ++lane) {
        int r = lane >> 2, c = lane & 3;
        int L  = (r == 0) ? 0 : (r < 4) ? 1 : (r < 9) ? 2 : 3;
        int li = r - L * L;
        int m_i = L - li;
        int am  = m_i < 0 ? -m_i : m_i;
        double sgn = (m_i < 0) ? -1.0 : 1.0;
        for (int s = 0; s < 7; ++s) {
            int ms  = 3 - s;
            int ams = ms < 0 ? -ms : ms;
            bool in = (ams <= L);
            int  kp = L - ms;
            T.t[lane][s]     = in ? (float)j_entry_d(L, li, kp) : 0.0f;
            T.t[lane][7 + s] = in ? (float)(sgn * j_entry_d(L, 2 * L - li, kp)) : 0.0f;
            for (int j = 0; j < 4; ++j) {
                int v = 4 * c + j - L * L;
                T.t[lane][14 + 4 * s + j] =
                    (in && v >= 0 && v <= 2 * L) ? (float)j_entry_d(L, kp, v) : 0.0f;
            }
        }
        T.t[lane][42] = (am == 0) ? 1.0f : 0.0f;
        T.t[lane][43] = (am == 1) ? 1.0f : 0.0f;
        T.t[lane][44] = (am == 2) ? 1.0f : 0.0f;
        T.t[lane][45] = (am == 3) ? 1.0f : 0.0f;
        T.t[lane][46] = 0.0f; T.t[lane][47] = 0.0f;
    }
    return T;
}

__device__ constexpr Tabs g_tabs = make_tabs();

struct LaneCst {
    float jmu[7], jrv[7], M[7][4];
    float sA0, sA1, sA2, sA3;
};

__device__ __forceinline__ vfloat4 edge_mat(float x, float y, float z, const LaneCst& C) {
    const float xx   = x * x;
    const float r2   = fmaf(z, z, fmaf(y, y, xx));
    const float rho2 = fmaf(y, y, xx);
    const float rinv = __builtin_amdgcn_rsqf(fmaxf(r2, 1e-30f));
    float cb = z * rinv;
    cb = fminf(fmaxf(cb, -1.0f + 1e-7f), 1.0f - 1e-7f);
    const float sb = __builtin_amdgcn_sqrtf(fmaxf(fmaf(-cb, cb, 1.0f), 0.0f));

    const float rhoinv = __builtin_amdgcn_rsqf(fmaxf(rho2, 1e-30f));
    const bool  nd  = rho2 >= 1e-14f;
    const float ca1 = nd ? x * rhoinv : 1.0f;
    const float sa1 = nd ? y * rhoinv : 0.0f;

    const float CA2 = fmaf(ca1, ca1, -(sa1 * sa1));
    const float SA2 = 2.0f * ca1 * sa1;
    const float CA3 = fmaf(CA2, ca1, -(SA2 * sa1));
    const float SA3 = fmaf(SA2, ca1, CA2 * sa1);
    const float CB2 = fmaf(cb, cb, -(sb * sb));
    const float SB2 = 2.0f * cb * sb;
    const float CB3 = fmaf(CB2, cb, -(SB2 * sb));
    const float SB3 = fmaf(SB2, cb, CB2 * sb);

    // cos/sin(|m_i| * alpha) via multiplicative per-lane masks
    float ca = fmaf(C.sA1, ca1, C.sA0);
    ca = fmaf(C.sA2, CA2, ca);
    ca = fmaf(C.sA3, CA3, ca);
    float sa = C.sA1 * sa1;
    sa = fmaf(C.sA2, SA2, sa);
    sa = fmaf(C.sA3, SA3, sa);          // sign(m_i) folded into jrv

    float u[7];
#pragma unroll
    for (int s = 0; s < 7; ++s) u[s] = fmaf(ca, C.jmu[s], sa * C.jrv[s]);

    float w[7];
    w[0] = fmaf(-u[6], SB3, u[0] * CB3);
    w[1] = fmaf(-u[5], SB2, u[1] * CB2);
    w[2] = fmaf(-u[4], sb , u[2] * cb );
    w[3] = u[3];
    w[4] = fmaf( u[2], sb , u[4] * cb );
    w[5] = fmaf( u[1], SB2, u[5] * CB2);
    w[6] = fmaf( u[0], SB3, u[6] * CB3);

    float a0 = 0.f, a1 = 0.f, a2 = 0.f, a3 = 0.f;
#pragma unroll
    for (int s = 0; s < 7; ++s) {
        a0 = fmaf(w[s], C.M[s][0], a0);
        a1 = fmaf(w[s], C.M[s][1], a1);
        a2 = fmaf(w[s], C.M[s][2], a2);
        a3 = fmaf(w[s], C.M[s][3], a3);
    }
    vfloat4 o; o.x = a0; o.y = a1; o.z = a2; o.w = a3;
    return o;
}

// One edge per wave; lane l stores floats [4l,4l+4) -> dense 1KB wave store.
// 4-edge unroll: 12 scalar coord loads hoisted, 4 independent nt stores in
// flight per iteration.
__global__ __launch_bounds__(256)
void EdgeRotation_49435073577214_kernel(const float* __restrict__ ev,
                                        float* __restrict__ out,
                                        int E, int nwaves) {
    const int lane = (int)(threadIdx.x & 63);
    int wv = (int)(blockIdx.x * (blockDim.x >> 6) + (threadIdx.x >> 6));
    wv = __builtin_amdgcn_readfirstlane(wv);          // uniform -> s_loads

    LaneCst C;
    const float* tp = g_tabs.t[lane];
#pragma unroll
    for (int s = 0; s < 7; ++s) { C.jmu[s] = tp[s]; C.jrv[s] = tp[7 + s]; }
#pragma unroll
    for (int s = 0; s < 7; ++s)
#pragma unroll
        for (int j = 0; j < 4; ++j) C.M[s][j] = tp[14 + 4 * s + j];
    C.sA0 = tp[42]; C.sA1 = tp[43]; C.sA2 = tp[44]; C.sA3 = tp[45];

    const int Em1 = E - 1;
    for (int e0 = wv; e0 < E; e0 += 4 * nwaves) {
        const int e1 = e0 + nwaves;
        const int e2 = e0 + 2 * nwaves;
        const int e3 = e0 + 3 * nwaves;
        const int c1 = e1 < E ? e1 : Em1;             // clamped load indices
        const int c2 = e2 < E ? e2 : Em1;
        const int c3 = e3 < E ? e3 : Em1;

        const float x0 = ev[3 * e0], y0 = ev[3 * e0 + 1], z0 = ev[3 * e0 + 2];
        const float x1 = ev[3 * c1], y1 = ev[3 * c1 + 1], z1 = ev[3 * c1 + 2];
        const float x2 = ev[3 * c2], y2 = ev[3 * c2 + 1], z2 = ev[3 * c2 + 2];
        const float x3 = ev[3 * c3], y3 = ev[3 * c3 + 1], z3 = ev[3 * c3 + 2];

        const vfloat4 o0 = edge_mat(x0, y0, z0, C);
        __builtin_nontemporal_store(o0,
            reinterpret_cast<vfloat4*>(out + ((size_t)e0 << 8)) + lane);

        const vfloat4 o1 = edge_mat(x1, y1, z1, C);
        if (e1 < E)
            __builtin_nontemporal_store(o1,
                reinterpret_cast<vfloat4*>(out + ((size_t)e1 << 8)) + lane);

        const vfloat4 o2 = edge_mat(x2, y2, z2, C);
        if (e2 < E)
            __builtin_nontemporal_store(o2,
                reinterpret_cast<vfloat4*>(out + ((size_t)e2 << 8)) + lane);

        const vfloat4 o3 = edge_mat(x3, y3, z3, C);
        if (e3 < E)
            __builtin_nontemporal_store(o3,
                reinterpret_cast<vfloat4*>(out + ((size_t)e3 << 8)) + lane);
    }
}

extern "C" void kernel_launch(void* const* d_in, const int* in_sizes, int n_in,
                              void* d_out, int out_size, void* d_ws, size_t ws_size,
                              hipStream_t stream) {
    const float* ev  = (const float*)d_in[0];
    float*       out = (float*)d_out;
    int E = in_sizes[0] / 3;   // [E,3] flat

    dim3 grid(2048), block(256);
    int nwaves = (int)((2048 * 256) / 64);
    hipLaunchKernelGGL(EdgeRotation_49435073577214_kernel, grid, block, 0, stream,
                       ev, out, E, nwaves);
}

// Round 6
// 101.082 us; speedup vs baseline: 1.0127x; 1.0127x over previous
//
#include <hip/hip_runtime.h>
#include <math.h>

typedef float vfloat4 __attribute__((ext_vector_type(4)));

// ---------------- compile-time J tables (reference _np_J, float64) ----------
constexpr double csqrt(double a) {
    double x = a > 1.0 ? a : 1.0;
    for (int i = 0; i < 48; ++i) x = 0.5 * (x + a / x);
    return x;
}

constexpr double j_entry_d(int ell, int mi, int mpi) {
    if (ell == 0) return 1.0;
    double fact[8] = {1.0, 1.0, 2.0, 6.0, 24.0, 120.0, 720.0, 5040.0};
    int m  = ell - mi;
    int mp = ell - mpi;
    double pref  = csqrt(fact[ell + m] * fact[ell - m] * fact[ell + mp] * fact[ell - mp]);
    double scale = 1.0 / (double)(1 << ell);
    int k0 = (m - mp) > 0 ? (m - mp) : 0;
    int k1 = (ell + m) < (ell - mp) ? (ell + m) : (ell - mp);
    double val = 0.0;
    for (int k = k0; k <= k1; ++k) {
        double denom = fact[ell + m - k] * fact[ell - mp - k] * fact[k + mp - m] * fact[k];
        double t = pref / denom * scale;
        val += ((m - mp + k) & 1) ? -t : t;
    }
    return (mi & 1) ? -val : val;
}

// Per-lane packed constants. Lane l: row r = l>>2, col group c = l&3.
// [0..6]   jmu[s]  = J_L[li,   L-m_s]            (m_s = 3-s; 0 outside block)
// [7..13]  jrv[s]  = sign(m_i) * J_L[2L-li, L-m_s]   (alpha sign pre-folded)
// [14..41] M[s][j] = J_L[L-m_s, 4c+j - L^2]      (0 outside block)
// [42..45] sA0..sA3 multiplicative masks for |m_i| == 0..3
struct alignas(16) Tabs { float t[64][48]; };

constexpr Tabs make_tabs() {
    Tabs T{};
    for (int lane = 0; lane < 64; ++lane) {
        int r = lane >> 2, c = lane & 3;
        int L  = (r == 0) ? 0 : (r < 4) ? 1 : (r < 9) ? 2 : 3;
        int li = r - L * L;
        int m_i = L - li;
        int am  = m_i < 0 ? -m_i : m_i;
        double sgn = (m_i < 0) ? -1.0 : 1.0;
        for (int s = 0; s < 7; ++s) {
            int ms  = 3 - s;
            int ams = ms < 0 ? -ms : ms;
            bool in = (ams <= L);
            int  kp = L - ms;
            T.t[lane][s]     = in ? (float)j_entry_d(L, li, kp) : 0.0f;
            T.t[lane][7 + s] = in ? (float)(sgn * j_entry_d(L, 2 * L - li, kp)) : 0.0f;
            for (int j = 0; j < 4; ++j) {
                int v = 4 * c + j - L * L;
                T.t[lane][14 + 4 * s + j] =
                    (in && v >= 0 && v <= 2 * L) ? (float)j_entry_d(L, kp, v) : 0.0f;
            }
        }
        T.t[lane][42] = (am == 0) ? 1.0f : 0.0f;
        T.t[lane][43] = (am == 1) ? 1.0f : 0.0f;
        T.t[lane][44] = (am == 2) ? 1.0f : 0.0f;
        T.t[lane][45] = (am == 3) ? 1.0f : 0.0f;
        T.t[lane][46] = 0.0f; T.t[lane][47] = 0.0f;
    }
    return T;
}

__device__ constexpr Tabs g_tabs = make_tabs();

struct LaneCst {
    float jmu[7], jrv[7], M[7][4];
    float sA0, sA1, sA2, sA3;
};

__device__ __forceinline__ vfloat4 edge_mat(float x, float y, float z, const LaneCst& C) {
    const float xx   = x * x;
    const float r2   = fmaf(z, z, fmaf(y, y, xx));
    const float rho2 = fmaf(y, y, xx);
    const float rinv = __builtin_amdgcn_rsqf(fmaxf(r2, 1e-30f));
    float cb = z * rinv;
    cb = fminf(fmaxf(cb, -1.0f + 1e-7f), 1.0f - 1e-7f);
    const float sb = __builtin_amdgcn_sqrtf(fmaxf(fmaf(-cb, cb, 1.0f), 0.0f));

    const float rhoinv = __builtin_amdgcn_rsqf(fmaxf(rho2, 1e-30f));
    const bool  nd  = rho2 >= 1e-14f;
    const float ca1 = nd ? x * rhoinv : 1.0f;
    const float sa1 = nd ? y * rhoinv : 0.0f;

    const float CA2 = fmaf(ca1, ca1, -(sa1 * sa1));
    const float SA2 = 2.0f * ca1 * sa1;
    const float CA3 = fmaf(CA2, ca1, -(SA2 * sa1));
    const float SA3 = fmaf(SA2, ca1, CA2 * sa1);
    const float CB2 = fmaf(cb, cb, -(sb * sb));
    const float SB2 = 2.0f * cb * sb;
    const float CB3 = fmaf(CB2, cb, -(SB2 * sb));
    const float SB3 = fmaf(SB2, cb, CB2 * sb);

    // cos/sin(|m_i| * alpha) via multiplicative per-lane masks
    float ca = fmaf(C.sA1, ca1, C.sA0);
    ca = fmaf(C.sA2, CA2, ca);
    ca = fmaf(C.sA3, CA3, ca);
    float sa = C.sA1 * sa1;
    sa = fmaf(C.sA2, SA2, sa);
    sa = fmaf(C.sA3, SA3, sa);          // sign(m_i) folded into jrv

    float u[7];
#pragma unroll
    for (int s = 0; s < 7; ++s) u[s] = fmaf(ca, C.jmu[s], sa * C.jrv[s]);

    float w[7];
    w[0] = fmaf(-u[6], SB3, u[0] * CB3);
    w[1] = fmaf(-u[5], SB2, u[1] * CB2);
    w[2] = fmaf(-u[4], sb , u[2] * cb );
    w[3] = u[3];
    w[4] = fmaf( u[2], sb , u[4] * cb );
    w[5] = fmaf( u[1], SB2, u[5] * CB2);
    w[6] = fmaf( u[0], SB3, u[6] * CB3);

    float a0 = 0.f, a1 = 0.f, a2 = 0.f, a3 = 0.f;
#pragma unroll
    for (int s = 0; s < 7; ++s) {
        a0 = fmaf(w[s], C.M[s][0], a0);
        a1 = fmaf(w[s], C.M[s][1], a1);
        a2 = fmaf(w[s], C.M[s][2], a2);
        a3 = fmaf(w[s], C.M[s][3], a3);
    }
    vfloat4 o; o.x = a0; o.y = a1; o.z = a2; o.w = a3;
    return o;
}

// One edge per wave; lane l stores floats [4l,4l+4) -> dense 1KB wave store.
// __launch_bounds__(256, 4): cap 4 waves/EU -> VGPR budget ~128 so the 46-float
// per-lane J-table stays REGISTER-RESIDENT (at the default target the compiler
// allocated 56 VGPRs and re-loaded the table from memory every edge).
__global__ __launch_bounds__(256, 4)
void EdgeRotation_49435073577214_kernel(const float* __restrict__ ev,
                                        float* __restrict__ out,
                                        int E, int nwaves) {
    const int lane = (int)(threadIdx.x & 63);
    int wv = (int)(blockIdx.x * (blockDim.x >> 6) + (threadIdx.x >> 6));
    wv = __builtin_amdgcn_readfirstlane(wv);          // uniform -> s_loads

    // vectorized table load: 12 x dwordx4 per lane (row is 192B, 16B aligned)
    LaneCst C;
    {
        const vfloat4* tv = reinterpret_cast<const vfloat4*>(g_tabs.t[lane]);
        vfloat4 q[12];
#pragma unroll
        for (int i = 0; i < 12; ++i) q[i] = tv[i];
        const float* tp = reinterpret_cast<const float*>(q);
#pragma unroll
        for (int s = 0; s < 7; ++s) { C.jmu[s] = tp[s]; C.jrv[s] = tp[7 + s]; }
#pragma unroll
        for (int s = 0; s < 7; ++s)
#pragma unroll
            for (int j = 0; j < 4; ++j) C.M[s][j] = tp[14 + 4 * s + j];
        C.sA0 = tp[42]; C.sA1 = tp[43]; C.sA2 = tp[44]; C.sA3 = tp[45];
    }

    const int Em1 = E - 1;
    for (int e0 = wv; e0 < E; e0 += 4 * nwaves) {
        const int e1 = e0 + nwaves;
        const int e2 = e0 + 2 * nwaves;
        const int e3 = e0 + 3 * nwaves;
        const int c1 = e1 < E ? e1 : Em1;             // clamped load indices
        const int c2 = e2 < E ? e2 : Em1;
        const int c3 = e3 < E ? e3 : Em1;

        const float x0 = ev[3 * e0], y0 = ev[3 * e0 + 1], z0 = ev[3 * e0 + 2];
        const float x1 = ev[3 * c1], y1 = ev[3 * c1 + 1], z1 = ev[3 * c1 + 2];
        const float x2 = ev[3 * c2], y2 = ev[3 * c2 + 1], z2 = ev[3 * c2 + 2];
        const float x3 = ev[3 * c3], y3 = ev[3 * c3 + 1], z3 = ev[3 * c3 + 2];

        const vfloat4 o0 = edge_mat(x0, y0, z0, C);
        __builtin_nontemporal_store(o0,
            reinterpret_cast<vfloat4*>(out + ((size_t)e0 << 8)) + lane);

        const vfloat4 o1 = edge_mat(x1, y1, z1, C);
        if (e1 < E)
            __builtin_nontemporal_store(o1,
                reinterpret_cast<vfloat4*>(out + ((size_t)e1 << 8)) + lane);

        const vfloat4 o2 = edge_mat(x2, y2, z2, C);
        if (e2 < E)
            __builtin_nontemporal_store(o2,
                reinterpret_cast<vfloat4*>(out + ((size_t)e2 << 8)) + lane);

        const vfloat4 o3 = edge_mat(x3, y3, z3, C);
        if (e3 < E)
            __builtin_nontemporal_store(o3,
                reinterpret_cast<vfloat4*>(out + ((size_t)e3 << 8)) + lane);
    }
}

extern "C" void kernel_launch(void* const* d_in, const int* in_sizes, int n_in,
                              void* d_out, int out_size, void* d_ws, size_t ws_size,
                              hipStream_t stream) {
    const float* ev  = (const float*)d_in[0];
    float*       out = (float*)d_out;
    int E = in_sizes[0] / 3;   // [E,3] flat

    dim3 grid(2048), block(256);
    int nwaves = (int)((2048 * 256) / 64);
    hipLaunchKernelGGL(EdgeRotation_49435073577214_kernel, grid, block, 0, stream,
                       ev, out, E, nwaves);
}

// Round 7
// 83.316 us; speedup vs baseline: 1.2287x; 1.2132x over previous
//
#include <hip/hip_runtime.h>
#include <math.h>

typedef float vfloat4 __attribute__((ext_vector_type(4)));

// ---------------- compile-time J tables (reference _np_J, float64) ----------
constexpr double csqrt(double a) {
    double x = a > 1.0 ? a : 1.0;
    for (int i = 0; i < 48; ++i) x = 0.5 * (x + a / x);
    return x;
}

constexpr double j_entry_d(int ell, int mi, int mpi) {
    if (ell == 0) return 1.0;
    double fact[8] = {1.0, 1.0, 2.0, 6.0, 24.0, 120.0, 720.0, 5040.0};
    int m  = ell - mi;
    int mp = ell - mpi;
    double pref  = csqrt(fact[ell + m] * fact[ell - m] * fact[ell + mp] * fact[ell - mp]);
    double scale = 1.0 / (double)(1 << ell);
    int k0 = (m - mp) > 0 ? (m - mp) : 0;
    int k1 = (ell + m) < (ell - mp) ? (ell + m) : (ell - mp);
    double val = 0.0;
    for (int k = k0; k <= k1; ++k) {
        double denom = fact[ell + m - k] * fact[ell - mp - k] * fact[k + mp - m] * fact[k];
        double t = pref / denom * scale;
        val += ((m - mp + k) & 1) ? -t : t;
    }
    return (mi & 1) ? -val : val;
}

// Per-ROW constants (16 rows of the 16x16 block-diag matrix).
// Row il: L, li = il - L^2, m_i = L - li. 7-slot m-frame, slot s <-> m_s = 3-s.
// [0..6]   jmu[s]  = J_L[li,   L-m_s]                 (0 outside block)
// [7..13]  jrv[s]  = sign(m_i)*J_L[2L-li, L-m_s]      (alpha sign pre-folded)
// [14..62] M[s][v] = J_L[L-m_s, v], v=0..6            (0 outside block)
// [63..66] sA0..sA3 multiplicative masks for |m_i| == 0..3
struct alignas(16) RowTabs { float t[16][68]; };

constexpr RowTabs make_tabs() {
    RowTabs T{};
    for (int il = 0; il < 16; ++il) {
        int L  = (il == 0) ? 0 : (il < 4) ? 1 : (il < 9) ? 2 : 3;
        int li = il - L * L;
        int m_i = L - li;
        int am  = m_i < 0 ? -m_i : m_i;
        double sgn = (m_i < 0) ? -1.0 : 1.0;
        for (int s = 0; s < 7; ++s) {
            int ms  = 3 - s;
            int ams = ms < 0 ? -ms : ms;
            bool in = (ams <= L);
            int  kp = L - ms;
            T.t[il][s]     = in ? (float)j_entry_d(L, li, kp) : 0.0f;
            T.t[il][7 + s] = in ? (float)(sgn * j_entry_d(L, 2 * L - li, kp)) : 0.0f;
            for (int v = 0; v < 7; ++v)
                T.t[il][14 + 7 * s + v] =
                    (in && v <= 2 * L) ? (float)j_entry_d(L, kp, v) : 0.0f;
        }
        T.t[il][63] = (am == 0) ? 1.0f : 0.0f;
        T.t[il][64] = (am == 1) ? 1.0f : 0.0f;
        T.t[il][65] = (am == 2) ? 1.0f : 0.0f;
        T.t[il][66] = (am == 3) ? 1.0f : 0.0f;
        T.t[il][67] = 0.0f;
    }
    return T;
}

__device__ constexpr RowTabs g_tabs = make_tabs();

// 4 edges per wave, 16 lanes per edge. Lane (g = lane>>4, il = lane&15)
// computes row il of edge e0+g (7 block values), scatters into a wave-private
// 4KB LDS region, then the wave reads back densely and issues 4 contiguous
// 1KB nontemporal stores. Same-wave LDS ops are in-order -> no barriers.
__global__ __launch_bounds__(256, 4)
void EdgeRotation_49435073577214_kernel(const float* __restrict__ ev,
                                        float* __restrict__ out,
                                        int E, int nwaves) {
    __shared__ float lds[4][1024];          // 4 waves/block x (4 edges x 256 f)

    const int tid  = (int)threadIdx.x;
    const int lane = tid & 63;
    const int wib  = tid >> 6;
    const int g    = lane >> 4;             // edge within quad
    const int il   = lane & 15;             // output row
    float* wlds = lds[wib];

    const int gw = (int)blockIdx.x * 4 + wib;   // global wave id

    // per-row constants -> registers (17 x dwordx4, one-time)
    float jmu[7], jrv[7], M[7][7], sA0, sA1, sA2, sA3;
    {
        const float* tp = g_tabs.t[il];
#pragma unroll
        for (int s = 0; s < 7; ++s) { jmu[s] = tp[s]; jrv[s] = tp[7 + s]; }
#pragma unroll
        for (int s = 0; s < 7; ++s)
#pragma unroll
            for (int v = 0; v < 7; ++v) M[s][v] = tp[14 + 7 * s + v];
        sA0 = tp[63]; sA1 = tp[64]; sA2 = tp[65]; sA3 = tp[66];
    }
    const int LL = (il == 0) ? 0 : (il < 4) ? 1 : (il < 9) ? 4 : 9;  // L^2
    float* pS = wlds + g * 256 + il * 16 + LL;   // scatter base for this lane

    const int Em1 = E - 1;
    for (int e0 = 4 * gw; e0 < E; e0 += 4 * nwaves) {
        int eg = e0 + g;
        eg = eg < E ? eg : Em1;                  // clamp (E%4==0 -> no-op)

        const float x = ev[3 * eg], y = ev[3 * eg + 1], z = ev[3 * eg + 2];

        // ---- angles (amortized over 4 edges/wave) ----
        const float xx   = x * x;
        const float r2   = fmaf(z, z, fmaf(y, y, xx));
        const float rho2 = fmaf(y, y, xx);
        const float rinv = __builtin_amdgcn_rsqf(fmaxf(r2, 1e-30f));
        float cbv = z * rinv;
        cbv = fminf(fmaxf(cbv, -1.0f + 1e-7f), 1.0f - 1e-7f);
        const float sbv = __builtin_amdgcn_sqrtf(fmaxf(fmaf(-cbv, cbv, 1.0f), 0.0f));
        const float rhoinv = __builtin_amdgcn_rsqf(fmaxf(rho2, 1e-30f));
        const bool  ndg = rho2 >= 1e-14f;
        const float ca1 = ndg ? x * rhoinv : 1.0f;
        const float sa1 = ndg ? y * rhoinv : 0.0f;

        const float CA2 = fmaf(ca1, ca1, -(sa1 * sa1));
        const float SA2 = 2.0f * ca1 * sa1;
        const float CA3 = fmaf(CA2, ca1, -(SA2 * sa1));
        const float SA3 = fmaf(SA2, ca1, CA2 * sa1);
        const float CB2 = fmaf(cbv, cbv, -(sbv * sbv));
        const float SB2 = 2.0f * cbv * sbv;
        const float CB3 = fmaf(CB2, cbv, -(SB2 * sbv));
        const float SB3 = fmaf(SB2, cbv, CB2 * sbv);

        // cos/sin(|m_i| alpha) via per-lane multiplicative masks
        float ca = fmaf(sA1, ca1, sA0);
        ca = fmaf(sA2, CA2, ca);
        ca = fmaf(sA3, CA3, ca);
        float sa = sA1 * sa1;
        sa = fmaf(sA2, SA2, sa);
        sa = fmaf(sA3, SA3, sa);                 // sign(m_i) folded into jrv

        float u[7];
#pragma unroll
        for (int s = 0; s < 7; ++s) u[s] = fmaf(ca, jmu[s], sa * jrv[s]);

        float w[7];
        w[0] = fmaf(-u[6], SB3, u[0] * CB3);
        w[1] = fmaf(-u[5], SB2, u[1] * CB2);
        w[2] = fmaf(-u[4], sbv, u[2] * cbv);
        w[3] = u[3];
        w[4] = fmaf( u[2], sbv, u[4] * cbv);
        w[5] = fmaf( u[1], SB2, u[5] * CB2);
        w[6] = fmaf( u[0], SB3, u[6] * CB3);

        // ---- zero-fill this wave's 4KB, then scatter 7 row values ----
        {
            vfloat4 zz; zz.x = 0.f; zz.y = 0.f; zz.z = 0.f; zz.w = 0.f;
            vfloat4* wv4 = reinterpret_cast<vfloat4*>(wlds);
            wv4[lane]       = zz;
            wv4[lane + 64]  = zz;
            wv4[lane + 128] = zz;
            wv4[lane + 192] = zz;
        }
#pragma unroll
        for (int v = 0; v < 7; ++v) {
            float d = 0.f;
#pragma unroll
            for (int s = 0; s < 7; ++s) d = fmaf(w[s], M[s][v], d);
            pS[v] = d;
        }

        // ---- dense read-back + 4 contiguous 1KB nt stores ----
        const vfloat4* rv4 = reinterpret_cast<const vfloat4*>(wlds);
        if (e0 + 4 <= E) {
#pragma unroll
            for (int q = 0; q < 4; ++q) {
                vfloat4 o = rv4[q * 64 + lane];
                __builtin_nontemporal_store(o,
                    reinterpret_cast<vfloat4*>(out) + (size_t)(e0 + q) * 64 + lane);
            }
        } else {
#pragma unroll
            for (int q = 0; q < 4; ++q) {
                if (e0 + q < E) {
                    vfloat4 o = rv4[q * 64 + lane];
                    __builtin_nontemporal_store(o,
                        reinterpret_cast<vfloat4*>(out) + (size_t)(e0 + q) * 64 + lane);
                }
            }
        }
    }
}

extern "C" void kernel_launch(void* const* d_in, const int* in_sizes, int n_in,
                              void* d_out, int out_size, void* d_ws, size_t ws_size,
                              hipStream_t stream) {
    const float* ev  = (const float*)d_in[0];
    float*       out = (float*)d_out;
    int E = in_sizes[0] / 3;   // [E,3] flat

    dim3 grid(2048), block(256);
    int nwaves = (int)((2048 * 256) / 64);
    hipLaunchKernelGGL(EdgeRotation_49435073577214_kernel, grid, block, 0, stream,
                       ev, out, E, nwaves);
}